// Round 8
// baseline (340.824 us; speedup 1.0000x reference)
//
#include <hip/hip_runtime.h>
#include <hip/hip_bf16.h>
#include <stdint.h>

#define BB 16
#define NN 4096
#define MM 1024
#define C1 128
#define C2 256
#define CIN 384
#define CO 256
#define ROWS (BB * NN)
#define NBLK 512  // mega grid: 256 CUs x exactly 2 blocks/CU (co-residency proof below)

typedef __attribute__((ext_vector_type(8))) short bf16x8;
typedef __attribute__((ext_vector_type(4))) float f32x4;

__device__ inline float u2f(uint32_t u) { union { uint32_t u; float f; } v; v.u = u; return v.f; }
__device__ inline uint32_t f2u(float f) { union { float f; uint32_t u; } v; v.f = f; return v.u; }
// round-to-nearest-even f32 -> bf16
__device__ inline unsigned short f2bf(float f) {
  uint32_t u = f2u(f);
  uint32_t r = u + 0x7fffu + ((u >> 16) & 1u);
  return (unsigned short)(r >> 16);
}
__device__ inline float bflo(uint32_t w) { return u2f(w << 16); }
__device__ inline float bfhi(uint32_t w) { return u2f(w & 0xffff0000u); }
// packed RNE f32x2 -> bf16x2 (v_cvt_pk_bf16_f32)
__device__ inline uint32_t pk2bf(float lo, float hi) {
  union { __hip_bfloat162 h; uint32_t u; } c;
  c.h = __float22bfloat162_rn(make_float2(lo, hi));
  return c.u;
}

// ---------------------------------------------------------------- three_nn
#define NN_INS(dd, jj_)                                        \
  {                                                            \
    bool c0 = (dd) < e0, c1 = (dd) < e1, c2 = (dd) < e2;       \
    e2 = c2 ? (c1 ? e1 : (dd)) : e2;                           \
    i2 = c2 ? (c1 ? i1 : (jj_)) : i2;                          \
    e1 = c1 ? (c0 ? e0 : (dd)) : e1;                           \
    i1 = c1 ? (c0 ? i0 : (jj_)) : i1;                          \
    e0 = c0 ? (dd) : e0;                                       \
    i0 = c0 ? (jj_) : i0;                                      \
  }

__global__ __launch_bounds__(256) void nn_kernel(const float* __restrict__ xyz1,
                                                 const float* __restrict__ xyz2,
                                                 int* __restrict__ idx,
                                                 float* __restrict__ wgt) {
  __shared__ float4 q[MM];  // 16 KB
  int b = blockIdx.x >> 7;                 // 128 blocks per batch (N/32)
  int qbase = (blockIdx.x & 127) << 5;     // 32 queries per block
  const float* x2 = xyz2 + (size_t)b * MM * 3;
  for (int j = threadIdx.x; j < MM; j += 256)
    q[j] = make_float4(x2[j * 3 + 0], x2[j * 3 + 1], x2[j * 3 + 2], 0.f);
  __syncthreads();
  int n = qbase + (threadIdx.x >> 3);
  int tq = threadIdx.x & 7;
  const float* p = xyz1 + ((size_t)b * NN + n) * 3;
  float px = p[0], py = p[1], pz = p[2];
  float e0 = 1e30f, e1 = 1e30f, e2 = 1e30f;
  int i0 = 0, i1 = 0, i2 = 0;
#pragma unroll 8
  for (int jj = 0; jj < MM / 8; ++jj) {
    int j = jj * 8 + tq;
    float4 qv = q[j];
    float dx = px - qv.x, dy = py - qv.y, dz = pz - qv.z;
    float d = dx * dx + dy * dy + dz * dz;
    NN_INS(d, j);
  }
#pragma unroll
  for (int mk = 1; mk <= 4; mk <<= 1) {
    float f0 = __shfl_xor(e0, mk), f1 = __shfl_xor(e1, mk), f2 = __shfl_xor(e2, mk);
    int j0 = __shfl_xor(i0, mk), j1 = __shfl_xor(i1, mk), j2 = __shfl_xor(i2, mk);
    NN_INS(f0, j0);
    NN_INS(f1, j1);
    NN_INS(f2, j2);
  }
  if (tq == 0) {
    float a0 = fmaxf(e0, 1e-10f), a1 = fmaxf(e1, 1e-10f), a2 = fmaxf(e2, 1e-10f);
    float v0 = 1.f / a0, v1 = 1.f / a1, v2 = 1.f / a2;
    float inv = 1.f / (v0 + v1 + v2);
    size_t base = ((size_t)b * NN + n) * 3;
    idx[base + 0] = i0; idx[base + 1] = i1; idx[base + 2] = i2;
    wgt[base + 0] = v0 * inv; wgt[base + 1] = v1 * inv; wgt[base + 2] = v2 * inv;
  }
}

// -------------------------------------------- interpolate + concat -> x bf16
__global__ __launch_bounds__(256) void interp_kernel(const float* __restrict__ points2,
                                                     const float* __restrict__ points1,
                                                     const int* __restrict__ idx,
                                                     const float* __restrict__ wgt,
                                                     unsigned short* __restrict__ X) {
  int row = blockIdx.x * 2 + (threadIdx.x >> 7);
  int t = threadIdx.x & 127;
  int b = row >> 12;  // N = 4096 rows per batch
  unsigned short* xr = X + (size_t)row * CIN;
  if (t < 64) {
    const int* id = idx + (size_t)row * 3;
    const float* w = wgt + (size_t)row * 3;
    const float* p2 = points2 + (size_t)b * MM * C2 + t * 4;
    float w0 = w[0], w1 = w[1], w2 = w[2];
    float4 a0 = *(const float4*)(p2 + (size_t)id[0] * C2);
    float4 a1 = *(const float4*)(p2 + (size_t)id[1] * C2);
    float4 a2 = *(const float4*)(p2 + (size_t)id[2] * C2);
    ushort4 o;
    o.x = f2bf(w0 * a0.x + w1 * a1.x + w2 * a2.x);
    o.y = f2bf(w0 * a0.y + w1 * a1.y + w2 * a2.y);
    o.z = f2bf(w0 * a0.z + w1 * a1.z + w2 * a2.z);
    o.w = f2bf(w0 * a0.w + w1 * a1.w + w2 * a2.w);
    *(ushort4*)(xr + t * 4) = o;
  } else if (t < 96) {
    int c = (t - 64) * 4;
    float4 a = *(const float4*)(points1 + (size_t)row * C1 + c);
    ushort4 o;
    o.x = f2bf(a.x); o.y = f2bf(a.y); o.z = f2bf(a.z); o.w = f2bf(a.w);
    *(ushort4*)(xr + C2 + c) = o;
  }
}

// ---------------- weight prep (fragment-stream layouts) + zero stats/barrier
// W0s: phase-1 B, PRE-SWIZZLED (rule #21: global_load_lds writes linearly, so
//   the T2 XOR swizzle is baked into the global layout). 16B unit index
//   u = kt*2048 + n*8 + cc  holds logical k-chunk c = cc ^ (n&7) of row n:
//   elems W0[kt*64 + c*8 + e][n], e=0..7.
// W1s: phase-2 B, K-tiles of 32 (64B rows -> naturally ~2-way, no swizzle):
//   u = kt*1024 + n*4 + c  holds W1[kt*32 + c*8 + e][n].
__global__ __launch_bounds__(256) void wt_prep(const float* __restrict__ W0,
                                               const float* __restrict__ W1,
                                               unsigned short* __restrict__ W0s,
                                               unsigned short* __restrict__ W1s,
                                               float* __restrict__ stats,
                                               int* __restrict__ bar) {
  int t = threadIdx.x, bid = blockIdx.x;
  if (bid == 0) {
    stats[t] = 0.f; stats[256 + t] = 0.f;
    if (t < 2) bar[t] = 0;
  }
  if (bid == 1) { stats[512 + t] = 0.f; stats[768 + t] = 0.f; }
  int u = bid * 256 + t;
  if (u < 12288) {  // W0s: 6 x 256 x 8 units
    int kt = u >> 11, r = u & 2047;
    int n = r >> 3, cc = r & 7;
    int c = cc ^ (n & 7);
    int k0 = kt * 64 + c * 8;
    unsigned short v[8];
#pragma unroll
    for (int e = 0; e < 8; ++e) v[e] = f2bf(W0[(size_t)(k0 + e) * CO + n]);
    *(uint4*)(W0s + (size_t)u * 8) = *(uint4*)v;
  } else if (u < 12288 + 8192) {  // W1s: 8 x 256 x 4 units
    int u2 = u - 12288;
    int kt = u2 >> 10, r = u2 & 1023;
    int n = r >> 2, c = r & 3;
    int k0 = kt * 32 + c * 8;
    unsigned short v[8];
#pragma unroll
    for (int e = 0; e < 8; ++e) v[e] = f2bf(W1[(size_t)(k0 + e) * CO + n]);
    *(uint4*)(W1s + (size_t)u2 * 8) = *(uint4*)v;
  }
}

// ------------------------------------------------------------- mega kernel
// One persistent kernel: gemm1 -> [grid barrier] -> BN1+ReLU on LDS slab ->
// gemm2 (A from LDS, W1 from L2) -> [grid barrier] -> BN2+ReLU from regs ->
// fp32 out. Y1/Y2 NEVER touch HBM (saves 136 MB traffic + 3 launch gaps).
//
// Co-residency proof (spin barrier is safe): grid = 512 = 256 CU x 2.
//   LDS 81920 B/block = exactly 160 KiB/2 -> max 2 blocks/CU, so blocks
//   spread exactly 2/CU and ALL 512 are resident before any can retire.
//   __launch_bounds__(256,2) caps VGPR at 256 (2 waves/SIMD). 8 waves/CU <= 32.
// Cross-block data crossing the barrier: ONLY the stats arrays, written with
// device-scope atomicAdd and read with agent-scope atomic loads (G16).
__device__ inline void gload_lds16(const void* g, void* l) {
  __builtin_amdgcn_global_load_lds(
      (const __attribute__((address_space(1))) void*)g,
      (__attribute__((address_space(3))) void*)l, 16, 0, 0);
}

__device__ inline void gridbar(int* b) {
  __syncthreads();
  if (threadIdx.x == 0) {
    __hip_atomic_fetch_add(b, 1, __ATOMIC_ACQ_REL, __HIP_MEMORY_SCOPE_AGENT);
    while (__hip_atomic_load(b, __ATOMIC_ACQUIRE, __HIP_MEMORY_SCOPE_AGENT) < NBLK) {
      __builtin_amdgcn_s_sleep(2);
    }
  }
  __syncthreads();
}

__global__ __launch_bounds__(256, 2) void mega(const unsigned short* __restrict__ X,
                                               const unsigned short* __restrict__ W0s,
                                               const unsigned short* __restrict__ W1s,
                                               const float* __restrict__ g0,
                                               const float* __restrict__ be0,
                                               const float* __restrict__ g1,
                                               const float* __restrict__ be1,
                                               float* __restrict__ stats,
                                               int* __restrict__ bar,
                                               float* __restrict__ out) {
  // LDS plan (81920 B total, phase-aliased):
  //   phase1 K-loop : lA [128][64] @0 (16K) | lB [256][64] @16K (32K)
  //   phase1 end    : slab [128][256] @0 (64K, chunk-rotated (c+row)&31)
  //   BN1 prep      : lscsh 512 f32 @64K (2K, transient)
  //   phase2 K-loop : slab @0 | lB2 [256][32] @64K (16K)
  __shared__ char ldsraw[81920];
  unsigned short* lA = (unsigned short*)ldsraw;
  unsigned short* lB = (unsigned short*)(ldsraw + 16384);
  unsigned short* slab = (unsigned short*)ldsraw;
  unsigned short* lB2 = (unsigned short*)(ldsraw + 65536);
  float* lscsh = (float*)(ldsraw + 65536);

  int t = threadIdx.x, lane = t & 63, w = t >> 6;
  int m0 = (int)blockIdx.x * 128;
  int lrow = lane >> 3, lcolA = ((lane & 7) ^ lrow) << 3;

  // ================= phase 1: acc = X[slab rows] * W0 =================
  f32x4 acc[8][4] = {};
  for (int kt = 0; kt < 6; ++kt) {
#pragma unroll
    for (int i = 0; i < 4; ++i) {
      int row = i * 32 + w * 8 + lrow;
      gload_lds16(X + (size_t)(m0 + row) * CIN + kt * 64 + lcolA,
                  lA + i * 2048 + w * 512);
    }
#pragma unroll
    for (int i = 0; i < 8; ++i) {
      gload_lds16(W0s + ((size_t)kt * 2048 + i * 256 + t) * 8,
                  lB + (i * 256 + w * 64) * 8);
    }
    __syncthreads();
#pragma unroll
    for (int kk = 0; kk < 2; ++kk) {
      int ko = kk * 32 + (lane >> 4) * 8;
      bf16x8 af[8], bfr[4];
#pragma unroll
      for (int m = 0; m < 8; ++m) {
        int row = m * 16 + (lane & 15);
        af[m] = *(const bf16x8*)&lA[row * 64 + (ko ^ ((row & 7) << 3))];
      }
#pragma unroll
      for (int n2 = 0; n2 < 4; ++n2) {
        int n = w * 64 + n2 * 16 + (lane & 15);
        bfr[n2] = *(const bf16x8*)&lB[n * 64 + (ko ^ ((n & 7) << 3))];
      }
#pragma unroll
      for (int m = 0; m < 8; ++m)
#pragma unroll
        for (int n2 = 0; n2 < 4; ++n2)
          acc[m][n2] = __builtin_amdgcn_mfma_f32_16x16x32_bf16(af[m], bfr[n2], acc[m][n2], 0, 0, 0);
    }
    __syncthreads();
  }

  // ---- stats1 (per-wave cols are disjoint -> atomicAdd global directly) ----
#pragma unroll
  for (int n2 = 0; n2 < 4; ++n2) {
    float s = 0.f, q = 0.f;
#pragma unroll
    for (int m = 0; m < 8; ++m)
#pragma unroll
      for (int j = 0; j < 4; ++j) { float v = acc[m][n2][j]; s += v; q += v * v; }
    s += __shfl_xor(s, 16); q += __shfl_xor(q, 16);
    s += __shfl_xor(s, 32); q += __shfl_xor(q, 32);
    if (lane < 16) {
      int col = w * 64 + n2 * 16 + lane;
      atomicAdd(&stats[col], s);
      atomicAdd(&stats[256 + col], q);
    }
  }
  // ---- acc -> LDS slab (raw bf16 Y1), chunk-rotated: phys = (c+row)&31 ----
#pragma unroll
  for (int m = 0; m < 8; ++m)
#pragma unroll
    for (int n2 = 0; n2 < 4; ++n2) {
      int col = w * 64 + n2 * 16 + (lane & 15);
#pragma unroll
      for (int j = 0; j < 4; ++j) {
        int row = m * 16 + (lane >> 4) * 4 + j;
        slab[row * 256 + ((((col >> 3) + row) & 31) << 3) + (col & 7)] = f2bf(acc[m][n2][j]);
      }
    }

  gridbar(&bar[0]);

  // ================= BN1 + ReLU rewrite of the slab =================
  {
    float sum = __hip_atomic_load(&stats[t], __ATOMIC_ACQUIRE, __HIP_MEMORY_SCOPE_AGENT);
    float sq = __hip_atomic_load(&stats[256 + t], __ATOMIC_ACQUIRE, __HIP_MEMORY_SCOPE_AGENT);
    float mean = sum * (1.f / ROWS);
    float var = sq * (1.f / ROWS) - mean * mean;
    float sc = g0[t] * rsqrtf(var + 1e-3f);
    lscsh[t] = sc;
    lscsh[256 + t] = be0[t] - mean * sc;
  }
  __syncthreads();
#pragma unroll
  for (int i = 0; i < 16; ++i) {
    int idx = i * 256 + t;
    int row = idx >> 5, p = idx & 31;
    int c = (p - row) & 31;                 // logical chunk -> channels c*8..c*8+7
    uint4 v = *(const uint4*)&slab[row * 256 + p * 8];
    float4 sa = *(const float4*)&lscsh[c * 8];
    float4 sb = *(const float4*)&lscsh[c * 8 + 4];
    float4 ha = *(const float4*)&lscsh[256 + c * 8];
    float4 hb = *(const float4*)&lscsh[256 + c * 8 + 4];
    uint32_t wv[4] = {v.x, v.y, v.z, v.w};
    float scf[8] = {sa.x, sa.y, sa.z, sa.w, sb.x, sb.y, sb.z, sb.w};
    float shf[8] = {ha.x, ha.y, ha.z, ha.w, hb.x, hb.y, hb.z, hb.w};
    uint32_t ov[4];
#pragma unroll
    for (int q = 0; q < 4; ++q) {
      float lo = fmaxf(bflo(wv[q]) * scf[2 * q] + shf[2 * q], 0.f);
      float hi = fmaxf(bfhi(wv[q]) * scf[2 * q + 1] + shf[2 * q + 1], 0.f);
      ov[q] = pk2bf(lo, hi);
    }
    uint4 o; o.x = ov[0]; o.y = ov[1]; o.z = ov[2]; o.w = ov[3];
    *(uint4*)&slab[row * 256 + p * 8] = o;
  }
  __syncthreads();  // slab final; lscsh dead (lB2 may overwrite)

  // ================= phase 2: acc2 = slab * W1 =================
  f32x4 acc2[8][4] = {};
  for (int kt2 = 0; kt2 < 8; ++kt2) {
#pragma unroll
    for (int i = 0; i < 4; ++i) {
      gload_lds16(W1s + ((size_t)kt2 * 1024 + i * 256 + t) * 8,
                  lB2 + (i * 256 + w * 64) * 8);
    }
    __syncthreads();
    int ko4 = lane >> 4;  // k-quad 0..3
    bf16x8 af[8], bfr[4];
#pragma unroll
    for (int m = 0; m < 8; ++m) {
      int row = m * 16 + (lane & 15);
      int phys = (kt2 * 4 + ko4 + row) & 31;
      af[m] = *(const bf16x8*)&slab[row * 256 + phys * 8];
    }
#pragma unroll
    for (int n2 = 0; n2 < 4; ++n2) {
      int n = w * 64 + n2 * 16 + (lane & 15);
      bfr[n2] = *(const bf16x8*)&lB2[n * 32 + ko4 * 8];
    }
#pragma unroll
    for (int m = 0; m < 8; ++m)
#pragma unroll
      for (int n2 = 0; n2 < 4; ++n2)
        acc2[m][n2] = __builtin_amdgcn_mfma_f32_16x16x32_bf16(af[m], bfr[n2], acc2[m][n2], 0, 0, 0);
    __syncthreads();
  }

  // ---- stats2 ----
#pragma unroll
  for (int n2 = 0; n2 < 4; ++n2) {
    float s = 0.f, q = 0.f;
#pragma unroll
    for (int m = 0; m < 8; ++m)
#pragma unroll
      for (int j = 0; j < 4; ++j) { float v = acc2[m][n2][j]; s += v; q += v * v; }
    s += __shfl_xor(s, 16); q += __shfl_xor(q, 16);
    s += __shfl_xor(s, 32); q += __shfl_xor(q, 32);
    if (lane < 16) {
      int col = w * 64 + n2 * 16 + lane;
      atomicAdd(&stats[512 + col], s);
      atomicAdd(&stats[768 + col], q);
    }
  }

  gridbar(&bar[1]);

  // ================= BN2 + ReLU from regs -> fp32 out =================
  float sc2[4], sh2[4];
#pragma unroll
  for (int n2 = 0; n2 < 4; ++n2) {
    int col = w * 64 + n2 * 16 + (lane & 15);
    float sum = __hip_atomic_load(&stats[512 + col], __ATOMIC_ACQUIRE, __HIP_MEMORY_SCOPE_AGENT);
    float sq = __hip_atomic_load(&stats[768 + col], __ATOMIC_ACQUIRE, __HIP_MEMORY_SCOPE_AGENT);
    float mean = sum * (1.f / ROWS);
    float var = sq * (1.f / ROWS) - mean * mean;
    sc2[n2] = g1[col] * rsqrtf(var + 1e-3f);
    sh2[n2] = be1[col] - mean * sc2[n2];
  }
#pragma unroll
  for (int m = 0; m < 8; ++m)
#pragma unroll
    for (int n2 = 0; n2 < 4; ++n2) {
      int col = w * 64 + n2 * 16 + (lane & 15);
#pragma unroll
      for (int j = 0; j < 4; ++j) {
        int row = m0 + m * 16 + (lane >> 4) * 4 + j;
        out[(size_t)row * CO + col] = fmaxf(acc2[m][n2][j] * sc2[n2] + sh2[n2], 0.f);
      }
    }
}

extern "C" void kernel_launch(void* const* d_in, const int* in_sizes, int n_in,
                              void* d_out, int out_size, void* d_ws, size_t ws_size,
                              hipStream_t stream) {
  const float* xyz1    = (const float*)d_in[0];
  const float* xyz2    = (const float*)d_in[1];
  const float* points1 = (const float*)d_in[2];
  const float* points2 = (const float*)d_in[3];
  const float* W0      = (const float*)d_in[4];
  const float* g0      = (const float*)d_in[6];
  const float* be0     = (const float*)d_in[7];
  const float* W1      = (const float*)d_in[8];
  const float* g1      = (const float*)d_in[10];
  const float* be1     = (const float*)d_in[11];
  float* out = (float*)d_out;

  // workspace layout (bytes)
  char* ws = (char*)d_ws;
  unsigned short* X   = (unsigned short*)(ws);                   // ROWS*384 bf16 = 50331648 B
  unsigned short* W0s = (unsigned short*)(ws + 50331648);        // 12288*16 B
  unsigned short* W1s = (unsigned short*)(ws + 50331648 + 196608);  // 8192*16 B
  float* stats = (float*)(ws + 50331648 + 196608 + 131072);      // 1024 f32
  int*   bar   = (int*)(stats + 1024);                           // 2 ints (pad 16)
  int*   idx   = (int*)((char*)bar + 16);                        // ROWS*3
  float* wgt   = (float*)(idx + ROWS * 3);                       // ROWS*3

  wt_prep<<<80, 256, 0, stream>>>(W0, W1, W0s, W1s, stats, bar);
  nn_kernel<<<BB * (NN / 32), 256, 0, stream>>>(xyz1, xyz2, idx, wgt);
  interp_kernel<<<ROWS / 2, 256, 0, stream>>>(points2, points1, idx, wgt, X);
  mega<<<NBLK, 256, 0, stream>>>(X, W0s, W1s, g0, be0, g1, be1, stats, bar, out);
}

// Round 9
// 143.660 us; speedup vs baseline: 2.3724x; 2.3724x over previous
//
#include <hip/hip_runtime.h>
#include <hip/hip_bf16.h>
#include <stdint.h>

#define BB 16
#define NN 4096
#define MM 1024
#define C1 128
#define C2 256
#define CIN 384
#define CO 256
#define ROWS (BB * NN)

typedef __attribute__((ext_vector_type(8))) short bf16x8;
typedef __attribute__((ext_vector_type(4))) float f32x4;

__device__ inline float u2f(uint32_t u) { union { uint32_t u; float f; } v; v.u = u; return v.f; }
__device__ inline uint32_t f2u(float f) { union { float f; uint32_t u; } v; v.f = f; return v.u; }
// round-to-nearest-even f32 -> bf16
__device__ inline unsigned short f2bf(float f) {
  uint32_t u = f2u(f);
  uint32_t r = u + 0x7fffu + ((u >> 16) & 1u);
  return (unsigned short)(r >> 16);
}
__device__ inline float bflo(uint32_t w) { return u2f(w << 16); }
__device__ inline float bfhi(uint32_t w) { return u2f(w & 0xffff0000u); }
// packed RNE f32x2 -> bf16x2 (v_cvt_pk_bf16_f32)
__device__ inline uint32_t pk2bf(float lo, float hi) {
  union { __hip_bfloat162 h; uint32_t u; } c;
  c.h = __float22bfloat162_rn(make_float2(lo, hi));
  return c.u;
}

// ---------------------------------------- three_nn + interp + concat (fused)
#define NN_INS(dd, jj_)                                        \
  {                                                            \
    bool c0 = (dd) < e0, c1 = (dd) < e1, c2 = (dd) < e2;       \
    e2 = c2 ? (c1 ? e1 : (dd)) : e2;                           \
    i2 = c2 ? (c1 ? i1 : (jj_)) : i2;                          \
    e1 = c1 ? (c0 ? e0 : (dd)) : e1;                           \
    i1 = c1 ? (c0 ? i0 : (jj_)) : i1;                          \
    e0 = c0 ? (dd) : e0;                                       \
    i0 = c0 ? (jj_) : i0;                                      \
  }

__global__ __launch_bounds__(256) void nn_interp(const float* __restrict__ xyz1,
                                                 const float* __restrict__ xyz2,
                                                 const float* __restrict__ points2,
                                                 const float* __restrict__ points1,
                                                 unsigned short* __restrict__ X) {
  __shared__ float4 q[MM];   // 16 KB
  __shared__ int sid[96];    // 32 queries x 3 neighbor ids
  __shared__ float swt[96];  // 32 queries x 3 weights
  int b = blockIdx.x >> 7;                 // 128 blocks per batch (N/32)
  int qbase = (blockIdx.x & 127) << 5;     // 32 queries per block
  const float* x2 = xyz2 + (size_t)b * MM * 3;
  for (int j = threadIdx.x; j < MM; j += 256)
    q[j] = make_float4(x2[j * 3 + 0], x2[j * 3 + 1], x2[j * 3 + 2], 0.f);
  __syncthreads();
  int n = qbase + (threadIdx.x >> 3);
  int tq = threadIdx.x & 7;
  const float* p = xyz1 + ((size_t)b * NN + n) * 3;
  float px = p[0], py = p[1], pz = p[2];
  float e0 = 1e30f, e1 = 1e30f, e2 = 1e30f;
  int i0 = 0, i1 = 0, i2 = 0;
#pragma unroll 8
  for (int jj = 0; jj < MM / 8; ++jj) {
    int j = jj * 8 + tq;
    float4 qv = q[j];
    float dx = px - qv.x, dy = py - qv.y, dz = pz - qv.z;
    float d = dx * dx + dy * dy + dz * dz;
    NN_INS(d, j);
  }
#pragma unroll
  for (int mk = 1; mk <= 4; mk <<= 1) {
    float f0 = __shfl_xor(e0, mk), f1 = __shfl_xor(e1, mk), f2 = __shfl_xor(e2, mk);
    int j0 = __shfl_xor(i0, mk), j1 = __shfl_xor(i1, mk), j2 = __shfl_xor(i2, mk);
    NN_INS(f0, j0);
    NN_INS(f1, j1);
    NN_INS(f2, j2);
  }
  if (tq == 0) {
    float a0 = fmaxf(e0, 1e-10f), a1 = fmaxf(e1, 1e-10f), a2 = fmaxf(e2, 1e-10f);
    float v0 = 1.f / a0, v1 = 1.f / a1, v2 = 1.f / a2;
    float inv = 1.f / (v0 + v1 + v2);
    int qi = threadIdx.x >> 3;
    sid[qi * 3 + 0] = i0; sid[qi * 3 + 1] = i1; sid[qi * 3 + 2] = i2;
    swt[qi * 3 + 0] = v0 * inv; swt[qi * 3 + 1] = v1 * inv; swt[qi * 3 + 2] = v2 * inv;
  }
  __syncthreads();
  // ---- interp + concat for this block's 32 rows ----
  // 32 rows x 48 chunks (8 bf16) = 1536 chunks; 6 per thread.
  const float* p2 = points2 + (size_t)b * MM * C2;
#pragma unroll
  for (int i = 0; i < 6; ++i) {
    int ci = i * 256 + threadIdx.x;
    int r = ci / 48, cc = ci - r * 48;
    size_t grow = (size_t)b * NN + qbase + r;
    unsigned short* xr = X + grow * CIN;
    unsigned short o[8];
    if (cc < 32) {
      int c0 = cc * 8;
      float w0 = swt[r * 3], w1 = swt[r * 3 + 1], w2 = swt[r * 3 + 2];
      const float* a0 = p2 + (size_t)sid[r * 3 + 0] * C2 + c0;
      const float* a1 = p2 + (size_t)sid[r * 3 + 1] * C2 + c0;
      const float* a2 = p2 + (size_t)sid[r * 3 + 2] * C2 + c0;
      float4 x0 = *(const float4*)a0, x1 = *(const float4*)(a0 + 4);
      float4 y0 = *(const float4*)a1, y1 = *(const float4*)(a1 + 4);
      float4 z0 = *(const float4*)a2, z1 = *(const float4*)(a2 + 4);
      o[0] = f2bf(w0 * x0.x + w1 * y0.x + w2 * z0.x);
      o[1] = f2bf(w0 * x0.y + w1 * y0.y + w2 * z0.y);
      o[2] = f2bf(w0 * x0.z + w1 * y0.z + w2 * z0.z);
      o[3] = f2bf(w0 * x0.w + w1 * y0.w + w2 * z0.w);
      o[4] = f2bf(w0 * x1.x + w1 * y1.x + w2 * z1.x);
      o[5] = f2bf(w0 * x1.y + w1 * y1.y + w2 * z1.y);
      o[6] = f2bf(w0 * x1.z + w1 * y1.z + w2 * z1.z);
      o[7] = f2bf(w0 * x1.w + w1 * y1.w + w2 * z1.w);
      *(uint4*)(xr + c0) = *(uint4*)o;
    } else {
      int c0 = (cc - 32) * 8;
      const float* a = points1 + grow * C1 + c0;
      float4 x0 = *(const float4*)a, x1 = *(const float4*)(a + 4);
      o[0] = f2bf(x0.x); o[1] = f2bf(x0.y); o[2] = f2bf(x0.z); o[3] = f2bf(x0.w);
      o[4] = f2bf(x1.x); o[5] = f2bf(x1.y); o[6] = f2bf(x1.z); o[7] = f2bf(x1.w);
      *(uint4*)(xr + C2 + c0) = *(uint4*)o;
    }
  }
}

// ---------------- both weight transposes + stats zeroing in ONE launch
__global__ __launch_bounds__(256) void wt_both(const float* __restrict__ W0,
                                               const float* __restrict__ W1,
                                               unsigned short* __restrict__ W0t,
                                               unsigned short* __restrict__ W1t,
                                               float* __restrict__ stats) {
  int t = threadIdx.x, bid = blockIdx.x;
  if (bid == 0) { stats[t] = 0.f; stats[256 + t] = 0.f; }
  if (bid == 1) { stats[512 + t] = 0.f; stats[768 + t] = 0.f; }
  if (bid < 384) {
    int i = bid * 256 + t;          // W0t index: [n][k], n = i/384, k = i%384
    int n = i / CIN, k = i - n * CIN;
    W0t[i] = f2bf(W0[(size_t)k * CO + n]);
  } else {
    int n = bid - 384;              // W1t[n][k], k = t
    W1t[n * CO + t] = f2bf(W1[(size_t)t * CO + n]);
  }
}

// ---------------------------------------------------------------- bf16 GEMM
// C[m][n] = sum_k A'[m][k] * Bt[n][k];  A' = FUSE ? relu(A*sc+sh) : A.
// Structure: block = 128 rows x 128-col panel, 4 waves each 32 rows x 128 cols.
//   A: global -> registers (4x dwordx4/tile/thread), issued ONE TILE AHEAD.
//   B: LDS double-buffer via global_load_lds (T2 source-side XOR swizzle),
//      next tile staged before current compute.
//   ONE __syncthreads per K-tile, placed AFTER compute: its vmcnt(0) drain
//   finds loads that aged under ~620 cyc of MFMA -> latency mostly hidden.
//   Loads sit before the barrier in program order so the compiler cannot
//   sink them to their uses (round-4 failure mode).
__device__ inline void gload_lds16(const void* g, void* l) {
  __builtin_amdgcn_global_load_lds(
      (const __attribute__((address_space(1))) void*)g,
      (__attribute__((address_space(3))) void*)l, 16, 0, 0);
}

template <int K, bool FUSE>
__global__ __launch_bounds__(256, 3) void gemm_nt(const unsigned short* __restrict__ A,
                                                  const unsigned short* __restrict__ Bt,
                                                  unsigned short* __restrict__ C,
                                                  float* __restrict__ stats,
                                                  const float* __restrict__ statsPrev,
                                                  const float* __restrict__ g,
                                                  const float* __restrict__ be) {
  constexpr int NT = K / 64;
  __shared__ unsigned short lB[2][128 * 64];  // 2 x 16 KB (cols-major [n][k], swizzled)
  __shared__ float sdat[256];                 // 128 col sums + 128 col sumsq
  __shared__ float lscsh[FUSE ? 512 : 4];     // BN scale[256] + shift[256]
  int t = threadIdx.x;
  int lane = t & 63, w = t >> 6;
  // pair-XCD swizzle: the two 128-col panels of one row-tile get bids 8 apart
  int gb = blockIdx.x >> 4, rb = blockIdx.x & 15;
  int pq = rb >> 3, ti = (gb << 3) + (rb & 7);
  int m0 = ti * 128, n0 = pq * 128;
  int lrow = lane >> 3;                       // 0..7
  int lcol = (((lane & 7) ^ lrow) << 3);      // swizzled source chunk * 8

#define STAGE_B(buf, tt_)                                                      \
  {                                                                            \
    _Pragma("unroll") for (int i = 0; i < 4; ++i) {                            \
      int row = i * 32 + w * 8 + lrow;                                         \
      gload_lds16(Bt + (size_t)(n0 + row) * K + (tt_) * 64 + lcol,             \
                  &lB[buf][i * 2048 + w * 512]);                               \
    }                                                                          \
  }

  // A base: this thread's two rows (m-frags) and k-chunk
  const unsigned short* Ab = A + (size_t)(m0 + w * 32 + (lane & 15)) * K + (lane >> 4) * 8;
  uint4 afc[4], afn[4];
  // afc[h*? ] layout: [0]=kk0 rows+0, [1]=kk0 rows+16, [2]=kk1 rows+0, [3]=kk1 rows+16
#define LOAD_A(dst, tt_)                                                       \
  {                                                                            \
    dst[0] = *(const uint4*)(Ab + (tt_) * 64);                                 \
    dst[1] = *(const uint4*)(Ab + (size_t)16 * K + (tt_) * 64);                \
    dst[2] = *(const uint4*)(Ab + (tt_) * 64 + 32);                            \
    dst[3] = *(const uint4*)(Ab + (size_t)16 * K + (tt_) * 64 + 32);           \
  }

  // prologue
  STAGE_B(0, 0);
  LOAD_A(afc, 0);
  sdat[t] = 0.f;
  if (FUSE) {
    float mean = statsPrev[t] * (1.f / ROWS);
    float var = statsPrev[256 + t] * (1.f / ROWS) - mean * mean;
    float sc = g[t] * rsqrtf(var + 1e-3f);
    lscsh[t] = sc;
    lscsh[256 + t] = be[t] - mean * sc;
  }
  __syncthreads();

  f32x4 acc[2][8] = {};

#define COMPUTE(buf, tt_)                                                      \
  {                                                                            \
    _Pragma("unroll") for (int kk = 0; kk < 2; ++kk) {                         \
      int ko = kk * 32 + (lane >> 4) * 8;                                      \
      bf16x8 bfr[8];                                                           \
      _Pragma("unroll") for (int n2 = 0; n2 < 8; ++n2) {                       \
        int row = n2 * 16 + (lane & 15);                                       \
        bfr[n2] = *(const bf16x8*)&lB[buf][row * 64 + (ko ^ ((row & 7) << 3))];\
      }                                                                        \
      bf16x8 af[2];                                                            \
      _Pragma("unroll") for (int m = 0; m < 2; ++m) {                          \
        union { uint4 u; bf16x8 h; uint32_t wv[4]; } cv;                       \
        cv.u = afc[kk * 2 + m];                                                \
        if (FUSE) {                                                            \
          int cb = (tt_) * 64 + ko;                                            \
          float4 sa = *(const float4*)&lscsh[cb];                              \
          float4 sb = *(const float4*)&lscsh[cb + 4];                          \
          float4 ha = *(const float4*)&lscsh[256 + cb];                        \
          float4 hb = *(const float4*)&lscsh[256 + cb + 4];                    \
          float scf[8] = {sa.x, sa.y, sa.z, sa.w, sb.x, sb.y, sb.z, sb.w};     \
          float shf[8] = {ha.x, ha.y, ha.z, ha.w, hb.x, hb.y, hb.z, hb.w};     \
          _Pragma("unroll") for (int q_ = 0; q_ < 4; ++q_) {                   \
            float lo = fmaxf(bflo(cv.wv[q_]) * scf[2 * q_] + shf[2 * q_], 0.f);\
            float hi = fmaxf(bfhi(cv.wv[q_]) * scf[2 * q_ + 1] + shf[2 * q_ + 1], 0.f); \
            cv.wv[q_] = pk2bf(lo, hi);                                         \
          }                                                                    \
        }                                                                      \
        af[m] = cv.h;                                                          \
      }                                                                        \
      _Pragma("unroll") for (int m = 0; m < 2; ++m)                            \
        _Pragma("unroll") for (int n2 = 0; n2 < 8; ++n2)                       \
          acc[m][n2] = __builtin_amdgcn_mfma_f32_16x16x32_bf16(af[m], bfr[n2], acc[m][n2], 0, 0, 0); \
    }                                                                          \
  }

#pragma unroll
  for (int tt = 0; tt < NT; ++tt) {
    if (tt + 1 < NT) {
      STAGE_B((tt + 1) & 1, tt + 1);   // issue next B tile (other buffer)
      LOAD_A(afn, tt + 1);             // issue next A tile to registers
    }
    COMPUTE(tt & 1, tt);               // ~620 cyc of MFMA hides the loads
    __syncthreads();                   // drain (loads are old) + publish LDS
    if (tt + 1 < NT) {
#pragma unroll
      for (int e = 0; e < 4; ++e) afc[e] = afn[e];
    }
  }
#undef STAGE_B
#undef LOAD_A
#undef COMPUTE

  // ---- C write (bf16, raw pre-BN values) ----
  int crow0 = m0 + w * 32 + (lane >> 4) * 4;
  int ccol0 = n0 + (lane & 15);
#pragma unroll
  for (int m = 0; m < 2; ++m)
#pragma unroll
    for (int n2 = 0; n2 < 8; ++n2) {
      size_t rb2 = (size_t)(crow0 + m * 16);
      int cc = ccol0 + n2 * 16;
#pragma unroll
      for (int j = 0; j < 4; ++j)
        C[(rb2 + j) * CO + cc] = f2bf(acc[m][n2][j]);
    }
  // ---- fused BN stats ----
#pragma unroll
  for (int n2 = 0; n2 < 8; ++n2) {
    float s = 0.f, qq = 0.f;
#pragma unroll
    for (int m = 0; m < 2; ++m)
#pragma unroll
      for (int j = 0; j < 4; ++j) { float v = acc[m][n2][j]; s += v; qq += v * v; }
    s += __shfl_xor(s, 16); qq += __shfl_xor(qq, 16);
    s += __shfl_xor(s, 32); qq += __shfl_xor(qq, 32);
    if (lane < 16) {
      int cl = n2 * 16 + lane;
      atomicAdd(&sdat[cl], s);
      atomicAdd(&sdat[128 + cl], qq);
    }
  }
  __syncthreads();
  if (t < 128) {
    atomicAdd(&stats[n0 + t], sdat[t]);
    atomicAdd(&stats[256 + n0 + t], sdat[128 + t]);
  }
}

// ------------------- BN+ReLU apply, fp32 out (finalize folded into prologue)
__global__ __launch_bounds__(256) void apply_f32(const unsigned short* __restrict__ Y,
                                                 const float* __restrict__ stats2,
                                                 const float* __restrict__ g,
                                                 const float* __restrict__ be,
                                                 float* __restrict__ out) {
  __shared__ float sc[256], sh[256];
  int t = threadIdx.x;
  {
    float mean = stats2[t] * (1.f / ROWS);
    float var = stats2[256 + t] * (1.f / ROWS) - mean * mean;
    float s = g[t] * rsqrtf(var + 1e-3f);
    sc[t] = s;
    sh[t] = be[t] - mean * s;
  }
  __syncthreads();
  size_t base = ((size_t)blockIdx.x * 256 + t) * 8;
  int c0 = (int)(base & 255);
  uint4 v = *(const uint4*)(Y + base);
  uint32_t wv[4] = {v.x, v.y, v.z, v.w};
  float o[8];
#pragma unroll
  for (int q = 0; q < 4; ++q) {
    o[2 * q]     = fmaxf(bflo(wv[q]) * sc[c0 + 2 * q] + sh[c0 + 2 * q], 0.f);
    o[2 * q + 1] = fmaxf(bfhi(wv[q]) * sc[c0 + 2 * q + 1] + sh[c0 + 2 * q + 1], 0.f);
  }
  *(float4*)(out + base) = make_float4(o[0], o[1], o[2], o[3]);
  *(float4*)(out + base + 4) = make_float4(o[4], o[5], o[6], o[7]);
}

extern "C" void kernel_launch(void* const* d_in, const int* in_sizes, int n_in,
                              void* d_out, int out_size, void* d_ws, size_t ws_size,
                              hipStream_t stream) {
  const float* xyz1    = (const float*)d_in[0];
  const float* xyz2    = (const float*)d_in[1];
  const float* points1 = (const float*)d_in[2];
  const float* points2 = (const float*)d_in[3];
  const float* W0      = (const float*)d_in[4];
  const float* g0      = (const float*)d_in[6];
  const float* be0     = (const float*)d_in[7];
  const float* W1      = (const float*)d_in[8];
  const float* g1      = (const float*)d_in[10];
  const float* be1     = (const float*)d_in[11];
  float* out = (float*)d_out;

  // workspace layout (bytes)
  char* ws = (char*)d_ws;
  unsigned short* X   = (unsigned short*)(ws);                       // ROWS*384 bf16 (reused for Y2)
  unsigned short* Y1  = (unsigned short*)(ws + 50331648);            // ROWS*256 bf16
  unsigned short* W0t = (unsigned short*)(ws + 50331648 + 33554432); // 384*256 bf16 (transposed)
  unsigned short* W1t = (unsigned short*)(ws + 50331648 + 33554432 + 196608);
  float* stats = (float*)(ws + 50331648 + 33554432 + 196608 + 131072); // 1024 f32
  unsigned short* Y2 = X;  // X buffer free after gemm1

  wt_both<<<640, 256, 0, stream>>>(W0, W1, W0t, W1t, stats);
  nn_interp<<<BB * (NN / 32), 256, 0, stream>>>(xyz1, xyz2, points2, points1, X);

  gemm_nt<CIN, false><<<1024, 256, 0, stream>>>(X, W0t, Y1, stats, nullptr, nullptr, nullptr);
  gemm_nt<CO, true><<<1024, 256, 0, stream>>>(Y1, W1t, Y2, stats + 512, stats, g0, be0);
  apply_f32<<<(size_t)ROWS * CO / (256 * 8), 256, 0, stream>>>(Y2, stats + 512, g1, be1, out);
}

// Round 10
// 137.422 us; speedup vs baseline: 2.4801x; 1.0454x over previous
//
#include <hip/hip_runtime.h>
#include <hip/hip_bf16.h>
#include <stdint.h>

#define BB 16
#define NN 4096
#define MM 1024
#define C1 128
#define C2 256
#define CIN 384
#define CO 256
#define ROWS (BB * NN)

typedef __attribute__((ext_vector_type(8))) short bf16x8;
typedef __attribute__((ext_vector_type(4))) float f32x4;

__device__ inline float u2f(uint32_t u) { union { uint32_t u; float f; } v; v.u = u; return v.f; }
__device__ inline uint32_t f2u(float f) { union { float f; uint32_t u; } v; v.f = f; return v.u; }
// round-to-nearest-even f32 -> bf16 (scalar; use pk2bf for pairs)
__device__ inline unsigned short f2bf(float f) {
  uint32_t u = f2u(f);
  uint32_t r = u + 0x7fffu + ((u >> 16) & 1u);
  return (unsigned short)(r >> 16);
}
__device__ inline float bflo(uint32_t w) { return u2f(w << 16); }
__device__ inline float bfhi(uint32_t w) { return u2f(w & 0xffff0000u); }
// packed RNE f32x2 -> bf16x2 (v_cvt_pk_bf16_f32; bit-identical to f2bf pair)
__device__ inline uint32_t pk2bf(float lo, float hi) {
  union { __hip_bfloat162 h; uint32_t u; } c;
  c.h = __float22bfloat162_rn(make_float2(lo, hi));
  return c.u;
}

// ------------------- three_nn + interp + concat + weight prep (one launch)
// Blocks 0..639: weight transpose strips + stats zeroing. Blocks 640..2687:
// NN search (8 thr/query, branchless top-3, shfl merge) + interp/concat.
#define NN_INS(dd, jj_)                                        \
  {                                                            \
    bool c0 = (dd) < e0, c1 = (dd) < e1, c2 = (dd) < e2;       \
    e2 = c2 ? (c1 ? e1 : (dd)) : e2;                           \
    i2 = c2 ? (c1 ? i1 : (jj_)) : i2;                          \
    e1 = c1 ? (c0 ? e0 : (dd)) : e1;                           \
    i1 = c1 ? (c0 ? i0 : (jj_)) : i1;                          \
    e0 = c0 ? (dd) : e0;                                       \
    i0 = c0 ? (jj_) : i0;                                      \
  }

__global__ __launch_bounds__(256) void nn_interp(const float* __restrict__ xyz1,
                                                 const float* __restrict__ xyz2,
                                                 const float* __restrict__ points2,
                                                 const float* __restrict__ points1,
                                                 const float* __restrict__ W0,
                                                 const float* __restrict__ W1,
                                                 unsigned short* __restrict__ W0t,
                                                 unsigned short* __restrict__ W1t,
                                                 float* __restrict__ stats,
                                                 unsigned short* __restrict__ X) {
  int t = threadIdx.x, bid = blockIdx.x;
  if (bid < 640) {  // ---- weight prep strips ----
    if (bid == 0) { stats[t] = 0.f; stats[256 + t] = 0.f; }
    if (bid == 1) { stats[512 + t] = 0.f; stats[768 + t] = 0.f; }
    if (bid < 384) {
      int i = bid * 256 + t;          // W0t[n][k]
      int n = i / CIN, k = i - n * CIN;
      W0t[i] = f2bf(W0[(size_t)k * CO + n]);
    } else {
      int n = bid - 384;              // W1t[n][k], k = t
      W1t[n * CO + t] = f2bf(W1[(size_t)t * CO + n]);
    }
    return;
  }
  __shared__ float4 q[MM];   // 16 KB
  __shared__ int sid[96];
  __shared__ float swt[96];
  int nb = bid - 640;
  int b = nb >> 7;                  // 128 blocks per batch
  int qbase = (nb & 127) << 5;      // 32 queries per block
  const float* x2 = xyz2 + (size_t)b * MM * 3;
  for (int j = t; j < MM; j += 256)
    q[j] = make_float4(x2[j * 3 + 0], x2[j * 3 + 1], x2[j * 3 + 2], 0.f);
  __syncthreads();
  int n = qbase + (t >> 3);
  int tq = t & 7;
  const float* p = xyz1 + ((size_t)b * NN + n) * 3;
  float px = p[0], py = p[1], pz = p[2];
  float e0 = 1e30f, e1 = 1e30f, e2 = 1e30f;
  int i0 = 0, i1 = 0, i2 = 0;
#pragma unroll 8
  for (int jj = 0; jj < MM / 8; ++jj) {
    int j = jj * 8 + tq;
    float4 qv = q[j];
    float dx = px - qv.x, dy = py - qv.y, dz = pz - qv.z;
    float d = dx * dx + dy * dy + dz * dz;
    NN_INS(d, j);
  }
#pragma unroll
  for (int mk = 1; mk <= 4; mk <<= 1) {
    float f0 = __shfl_xor(e0, mk), f1 = __shfl_xor(e1, mk), f2 = __shfl_xor(e2, mk);
    int j0 = __shfl_xor(i0, mk), j1 = __shfl_xor(i1, mk), j2 = __shfl_xor(i2, mk);
    NN_INS(f0, j0);
    NN_INS(f1, j1);
    NN_INS(f2, j2);
  }
  if (tq == 0) {
    float a0 = fmaxf(e0, 1e-10f), a1 = fmaxf(e1, 1e-10f), a2 = fmaxf(e2, 1e-10f);
    float v0 = 1.f / a0, v1 = 1.f / a1, v2 = 1.f / a2;
    float inv = 1.f / (v0 + v1 + v2);
    int qi = t >> 3;
    sid[qi * 3 + 0] = i0; sid[qi * 3 + 1] = i1; sid[qi * 3 + 2] = i2;
    swt[qi * 3 + 0] = v0 * inv; swt[qi * 3 + 1] = v1 * inv; swt[qi * 3 + 2] = v2 * inv;
  }
  __syncthreads();
  // ---- interp + concat: 32 rows x 48 chunks(8 bf16) = 1536; 6 per thread ----
  const float* p2 = points2 + (size_t)b * MM * C2;
#pragma unroll
  for (int i = 0; i < 6; ++i) {
    int ci = i * 256 + t;
    int r = ci / 48, cc = ci - r * 48;
    size_t grow = (size_t)b * NN + qbase + r;
    unsigned short* xr = X + grow * CIN;
    uint4 o4;
    if (cc < 32) {
      int c0 = cc * 8;
      float w0 = swt[r * 3], w1 = swt[r * 3 + 1], w2 = swt[r * 3 + 2];
      const float* a0 = p2 + (size_t)sid[r * 3 + 0] * C2 + c0;
      const float* a1 = p2 + (size_t)sid[r * 3 + 1] * C2 + c0;
      const float* a2 = p2 + (size_t)sid[r * 3 + 2] * C2 + c0;
      float4 x0 = *(const float4*)a0, x1 = *(const float4*)(a0 + 4);
      float4 y0 = *(const float4*)a1, y1 = *(const float4*)(a1 + 4);
      float4 z0 = *(const float4*)a2, z1 = *(const float4*)(a2 + 4);
      o4.x = pk2bf(w0 * x0.x + w1 * y0.x + w2 * z0.x, w0 * x0.y + w1 * y0.y + w2 * z0.y);
      o4.y = pk2bf(w0 * x0.z + w1 * y0.z + w2 * z0.z, w0 * x0.w + w1 * y0.w + w2 * z0.w);
      o4.z = pk2bf(w0 * x1.x + w1 * y1.x + w2 * z1.x, w0 * x1.y + w1 * y1.y + w2 * z1.y);
      o4.w = pk2bf(w0 * x1.z + w1 * y1.z + w2 * z1.z, w0 * x1.w + w1 * y1.w + w2 * z1.w);
      *(uint4*)(xr + c0) = o4;
    } else {
      int c0 = (cc - 32) * 8;
      const float* a = points1 + grow * C1 + c0;
      float4 x0 = *(const float4*)a, x1 = *(const float4*)(a + 4);
      o4.x = pk2bf(x0.x, x0.y); o4.y = pk2bf(x0.z, x0.w);
      o4.z = pk2bf(x1.x, x1.y); o4.w = pk2bf(x1.z, x1.w);
      *(uint4*)(xr + C2 + c0) = o4;
    }
  }
}

// ---------------------------------------------------------------- bf16 GEMM
// C[m][n] = sum_k A'[m][k] * Bt[n][k];  A' = FUSE ? relu(A*sc+sh) : A.
// Ping-pong A regs (afA/afB, no copies) + counted vmcnt before raw s_barrier:
// s_waitcnt vmcnt(4) waits ONLY the 4 older gload_lds (B stage); the 4 newer
// A-register loads stay in flight across the barrier (T4 minimum form).
// Issue order STAGE_B -> LOAD_A is pinned by asm "memory" clobbers so the
// vmcnt count is deterministic. NT is even for both K (6, 4).
__device__ inline void gload_lds16(const void* g, void* l) {
  __builtin_amdgcn_global_load_lds(
      (const __attribute__((address_space(1))) void*)g,
      (__attribute__((address_space(3))) void*)l, 16, 0, 0);
}

template <int K, bool FUSE>
__global__ __launch_bounds__(256, 3) void gemm_nt(const unsigned short* __restrict__ A,
                                                  const unsigned short* __restrict__ Bt,
                                                  unsigned short* __restrict__ C,
                                                  float* __restrict__ stats,
                                                  const float* __restrict__ statsPrev,
                                                  const float* __restrict__ g,
                                                  const float* __restrict__ be) {
  constexpr int NT = K / 64;
  __shared__ unsigned short lB[2][128 * 64];  // [buf][n][k] swizzled chunks
  __shared__ float sdat[256];
  __shared__ float lscsh[FUSE ? 512 : 4];
  int t = threadIdx.x;
  int lane = t & 63, w = t >> 6;
  // pair-XCD swizzle: the two 128-col panels of one row-tile get bids 8 apart
  int gb = blockIdx.x >> 4, rb = blockIdx.x & 15;
  int pq = rb >> 3, ti = (gb << 3) + (rb & 7);
  int m0 = ti * 128, n0 = pq * 128;
  int lrow = lane >> 3;                       // 0..7
  int lcol = (((lane & 7) ^ lrow) << 3);      // T2 source-side swizzled chunk

#define STAGE_B(buf, tt_)                                                      \
  {                                                                            \
    _Pragma("unroll") for (int i = 0; i < 4; ++i) {                            \
      int row = i * 32 + w * 8 + lrow;                                         \
      gload_lds16(Bt + (size_t)(n0 + row) * K + (tt_) * 64 + lcol,             \
                  &lB[buf][i * 2048 + w * 512]);                               \
    }                                                                          \
    asm volatile("" ::: "memory");  /* pin issue order: gloads before A */     \
  }

  const unsigned short* Ab = A + (size_t)(m0 + w * 32 + (lane & 15)) * K + (lane >> 4) * 8;
#define LOAD_A(dst, tt_)                                                       \
  {                                                                            \
    dst[0] = *(const uint4*)(Ab + (tt_) * 64);                                 \
    dst[1] = *(const uint4*)(Ab + (size_t)16 * K + (tt_) * 64);                \
    dst[2] = *(const uint4*)(Ab + (tt_) * 64 + 32);                            \
    dst[3] = *(const uint4*)(Ab + (size_t)16 * K + (tt_) * 64 + 32);           \
  }

  uint4 afA[4], afB[4];
  STAGE_B(0, 0);
  LOAD_A(afA, 0);
  sdat[t] = 0.f;
  if (FUSE) {
    float mean = statsPrev[t] * (1.f / ROWS);
    float var = statsPrev[256 + t] * (1.f / ROWS) - mean * mean;
    float sc = g[t] * rsqrtf(var + 1e-3f);
    lscsh[t] = sc;
    lscsh[256 + t] = be[t] - mean * sc;
  }
  __syncthreads();  // prologue: full drain, B(0) visible

  f32x4 acc[2][8] = {};

#define COMPUTE(buf, tt_, AF)                                                  \
  {                                                                            \
    _Pragma("unroll") for (int kk = 0; kk < 2; ++kk) {                         \
      int ko = kk * 32 + (lane >> 4) * 8;                                      \
      bf16x8 bfr[8];                                                           \
      _Pragma("unroll") for (int n2 = 0; n2 < 8; ++n2) {                       \
        int row = n2 * 16 + (lane & 15);                                       \
        bfr[n2] = *(const bf16x8*)&lB[buf][row * 64 + (ko ^ ((row & 7) << 3))];\
      }                                                                        \
      bf16x8 af[2];                                                            \
      _Pragma("unroll") for (int m = 0; m < 2; ++m) {                          \
        union { uint4 u; bf16x8 h; uint32_t wv[4]; } cv;                       \
        cv.u = AF[kk * 2 + m];                                                 \
        if (FUSE) {                                                            \
          int cb = (tt_) * 64 + ko;                                            \
          float4 sa = *(const float4*)&lscsh[cb];                              \
          float4 sb = *(const float4*)&lscsh[cb + 4];                          \
          float4 ha = *(const float4*)&lscsh[256 + cb];                        \
          float4 hb = *(const float4*)&lscsh[256 + cb + 4];                    \
          float scf[8] = {sa.x, sa.y, sa.z, sa.w, sb.x, sb.y, sb.z, sb.w};     \
          float shf[8] = {ha.x, ha.y, ha.z, ha.w, hb.x, hb.y, hb.z, hb.w};     \
          _Pragma("unroll") for (int q_ = 0; q_ < 4; ++q_) {                   \
            float lo = fmaxf(bflo(cv.wv[q_]) * scf[2 * q_] + shf[2 * q_], 0.f);\
            float hi = fmaxf(bfhi(cv.wv[q_]) * scf[2 * q_ + 1] + shf[2 * q_ + 1], 0.f); \
            cv.wv[q_] = pk2bf(lo, hi);                                         \
          }                                                                    \
        }                                                                      \
        af[m] = cv.h;                                                          \
      }                                                                        \
      _Pragma("unroll") for (int m = 0; m < 2; ++m)                            \
        _Pragma("unroll") for (int n2 = 0; n2 < 8; ++n2)                       \
          acc[m][n2] = __builtin_amdgcn_mfma_f32_16x16x32_bf16(af[m], bfr[n2], acc[m][n2], 0, 0, 0); \
    }                                                                          \
  }

#define CBAR()                                                                 \
  {                                                                            \
    asm volatile("s_waitcnt vmcnt(4)" ::: "memory");                           \
    __builtin_amdgcn_s_barrier();                                              \
  }

#pragma unroll
  for (int tt = 0; tt < NT; tt += 2) {
    STAGE_B(1, tt + 1);
    LOAD_A(afB, tt + 1);
    COMPUTE(0, tt, afA);
    CBAR();
    if (tt + 2 < NT) {
      STAGE_B(0, tt + 2);
      LOAD_A(afA, tt + 2);
    }
    COMPUTE(1, tt + 1, afB);
    if (tt + 2 < NT) CBAR();
  }
#undef STAGE_B
#undef LOAD_A
#undef COMPUTE
#undef CBAR

  // ---- C write (bf16, raw pre-BN values) ----
  int crow0 = m0 + w * 32 + (lane >> 4) * 4;
  int ccol0 = n0 + (lane & 15);
#pragma unroll
  for (int m = 0; m < 2; ++m)
#pragma unroll
    for (int n2 = 0; n2 < 8; ++n2) {
      size_t rb2 = (size_t)(crow0 + m * 16);
      int cc = ccol0 + n2 * 16;
#pragma unroll
      for (int j = 0; j < 4; ++j)
        C[(rb2 + j) * CO + cc] = f2bf(acc[m][n2][j]);
    }
  // ---- fused BN stats ----
#pragma unroll
  for (int n2 = 0; n2 < 8; ++n2) {
    float s = 0.f, qq = 0.f;
#pragma unroll
    for (int m = 0; m < 2; ++m)
#pragma unroll
      for (int j = 0; j < 4; ++j) { float v = acc[m][n2][j]; s += v; qq += v * v; }
    s += __shfl_xor(s, 16); qq += __shfl_xor(qq, 16);
    s += __shfl_xor(s, 32); qq += __shfl_xor(qq, 32);
    if (lane < 16) {
      int cl = n2 * 16 + lane;
      atomicAdd(&sdat[cl], s);
      atomicAdd(&sdat[128 + cl], qq);
    }
  }
  __syncthreads();
  if (t < 128) {
    atomicAdd(&stats[n0 + t], sdat[t]);
    atomicAdd(&stats[256 + n0 + t], sdat[128 + t]);
  }
}

// ------------------- BN+ReLU apply, fp32 out (finalize folded into prologue)
__global__ __launch_bounds__(256) void apply_f32(const unsigned short* __restrict__ Y,
                                                 const float* __restrict__ stats2,
                                                 const float* __restrict__ g,
                                                 const float* __restrict__ be,
                                                 float* __restrict__ out) {
  __shared__ float sc[256], sh[256];
  int t = threadIdx.x;
  {
    float mean = stats2[t] * (1.f / ROWS);
    float var = stats2[256 + t] * (1.f / ROWS) - mean * mean;
    float s = g[t] * rsqrtf(var + 1e-3f);
    sc[t] = s;
    sh[t] = be[t] - mean * s;
  }
  __syncthreads();
  size_t base = ((size_t)blockIdx.x * 256 + t) * 8;
  int c0 = (int)(base & 255);
  uint4 v = *(const uint4*)(Y + base);
  uint32_t wv[4] = {v.x, v.y, v.z, v.w};
  float o[8];
#pragma unroll
  for (int q = 0; q < 4; ++q) {
    o[2 * q]     = fmaxf(bflo(wv[q]) * sc[c0 + 2 * q] + sh[c0 + 2 * q], 0.f);
    o[2 * q + 1] = fmaxf(bfhi(wv[q]) * sc[c0 + 2 * q + 1] + sh[c0 + 2 * q + 1], 0.f);
  }
  *(float4*)(out + base) = make_float4(o[0], o[1], o[2], o[3]);
  *(float4*)(out + base + 4) = make_float4(o[4], o[5], o[6], o[7]);
}

extern "C" void kernel_launch(void* const* d_in, const int* in_sizes, int n_in,
                              void* d_out, int out_size, void* d_ws, size_t ws_size,
                              hipStream_t stream) {
  const float* xyz1    = (const float*)d_in[0];
  const float* xyz2    = (const float*)d_in[1];
  const float* points1 = (const float*)d_in[2];
  const float* points2 = (const float*)d_in[3];
  const float* W0      = (const float*)d_in[4];
  const float* g0      = (const float*)d_in[6];
  const float* be0     = (const float*)d_in[7];
  const float* W1      = (const float*)d_in[8];
  const float* g1      = (const float*)d_in[10];
  const float* be1     = (const float*)d_in[11];
  float* out = (float*)d_out;

  // workspace layout (bytes)
  char* ws = (char*)d_ws;
  unsigned short* X   = (unsigned short*)(ws);                       // ROWS*384 bf16 (reused for Y2)
  unsigned short* Y1  = (unsigned short*)(ws + 50331648);            // ROWS*256 bf16
  unsigned short* W0t = (unsigned short*)(ws + 50331648 + 33554432); // 384*256 bf16 (transposed)
  unsigned short* W1t = (unsigned short*)(ws + 50331648 + 33554432 + 196608);
  float* stats = (float*)(ws + 50331648 + 33554432 + 196608 + 131072); // 1024 f32
  unsigned short* Y2 = X;  // X buffer free after gemm1

  nn_interp<<<640 + BB * (NN / 32), 256, 0, stream>>>(xyz1, xyz2, points2, points1,
                                                      W0, W1, W0t, W1t, stats, X);
  gemm_nt<CIN, false><<<1024, 256, 0, stream>>>(X, W0t, Y1, stats, nullptr, nullptr, nullptr);
  gemm_nt<CO, true><<<1024, 256, 0, stream>>>(Y1, W1t, Y2, stats + 512, stats, g0, be0);
  apply_f32<<<(size_t)ROWS * CO / (256 * 8), 256, 0, stream>>>(Y2, stats + 512, g1, be1, out);
}

// Round 11
// 128.250 us; speedup vs baseline: 2.6575x; 1.0715x over previous
//
#include <hip/hip_runtime.h>
#include <hip/hip_bf16.h>
#include <stdint.h>

#define BB 16
#define NN 4096
#define MM 1024
#define C1 128
#define C2 256
#define CIN 384
#define CO 256
#define ROWS (BB * NN)

typedef __attribute__((ext_vector_type(8))) short bf16x8;
typedef __attribute__((ext_vector_type(4))) float f32x4;

__device__ inline float u2f(uint32_t u) { union { uint32_t u; float f; } v; v.u = u; return v.f; }
__device__ inline uint32_t f2u(float f) { union { float f; uint32_t u; } v; v.f = f; return v.u; }
// round-to-nearest-even f32 -> bf16 (scalar; use pk2bf for pairs)
__device__ inline unsigned short f2bf(float f) {
  uint32_t u = f2u(f);
  uint32_t r = u + 0x7fffu + ((u >> 16) & 1u);
  return (unsigned short)(r >> 16);
}
__device__ inline float bflo(uint32_t w) { return u2f(w << 16); }
__device__ inline float bfhi(uint32_t w) { return u2f(w & 0xffff0000u); }
// packed RNE f32x2 -> bf16x2 (v_cvt_pk_bf16_f32; bit-identical to f2bf pair)
__device__ inline uint32_t pk2bf(float lo, float hi) {
  union { __hip_bfloat162 h; uint32_t u; } c;
  c.h = __float22bfloat162_rn(make_float2(lo, hi));
  return c.u;
}

// ------------------- three_nn + interp + concat + weight prep (one launch)
// Sorted top-3 insert via v_med3_f32 (bit-exact selection, no rounding):
// with e0<=e1<=e2, the 3 smallest of {e0,e1,e2,d} are
//   e0'=min(e0,d), e1'=med3(e0,e1,d), e2'=med3(e1,e2,d)  -- 3 chain-free insts
// (replaces 10 dependent cndmasks). Index updates use conditions vs OLD e's,
// written in order i2 -> i1 -> i0 so old i1/i0 are still live.
#define NN_INS(dd, jj_)                                            \
  {                                                                \
    bool c0 = (dd) < e0, c1 = (dd) < e1, c2 = (dd) < e2;           \
    e2 = __builtin_amdgcn_fmed3f(e1, e2, (dd));                    \
    e1 = __builtin_amdgcn_fmed3f(e0, e1, (dd));                    \
    e0 = fminf(e0, (dd));                                          \
    i2 = c2 ? (c1 ? i1 : (jj_)) : i2;                              \
    i1 = c1 ? (c0 ? i0 : (jj_)) : i1;                              \
    i0 = c0 ? (jj_) : i0;                                          \
  }

__global__ __launch_bounds__(256) void nn_interp(const float* __restrict__ xyz1,
                                                 const float* __restrict__ xyz2,
                                                 const float* __restrict__ points2,
                                                 const float* __restrict__ points1,
                                                 const float* __restrict__ W0,
                                                 const float* __restrict__ W1,
                                                 unsigned short* __restrict__ W0t,
                                                 unsigned short* __restrict__ W1t,
                                                 float* __restrict__ stats,
                                                 unsigned short* __restrict__ X) {
  int t = threadIdx.x, bid = blockIdx.x;
  if (bid < 640) {  // ---- weight prep strips ----
    if (bid == 0) { stats[t] = 0.f; stats[256 + t] = 0.f; }
    if (bid == 1) { stats[512 + t] = 0.f; stats[768 + t] = 0.f; }
    if (bid < 384) {
      int i = bid * 256 + t;          // W0t[n][k]
      int n = i / CIN, k = i - n * CIN;
      W0t[i] = f2bf(W0[(size_t)k * CO + n]);
    } else {
      int n = bid - 384;              // W1t[n][k], k = t
      W1t[n * CO + t] = f2bf(W1[(size_t)t * CO + n]);
    }
    return;
  }
  __shared__ float4 q[MM];   // 16 KB
  __shared__ int sid[96];
  __shared__ float swt[96];
  int nb = bid - 640;
  int b = nb >> 7;                  // 128 blocks per batch
  int qbase = (nb & 127) << 5;      // 32 queries per block
  const float* x2 = xyz2 + (size_t)b * MM * 3;
  for (int j = t; j < MM; j += 256)
    q[j] = make_float4(x2[j * 3 + 0], x2[j * 3 + 1], x2[j * 3 + 2], 0.f);
  __syncthreads();
  int n = qbase + (t >> 3);
  int tq = t & 7;
  const float* p = xyz1 + ((size_t)b * NN + n) * 3;
  float px = p[0], py = p[1], pz = p[2];
  float e0 = 1e30f, e1 = 1e30f, e2 = 1e30f;
  int i0 = 0, i1 = 0, i2 = 0;
#pragma unroll 8
  for (int jj = 0; jj < MM / 8; ++jj) {
    int j = jj * 8 + tq;
    float4 qv = q[j];
    float dx = px - qv.x, dy = py - qv.y, dz = pz - qv.z;
    float d = dx * dx + dy * dy + dz * dz;
    NN_INS(d, j);
  }
#pragma unroll
  for (int mk = 1; mk <= 4; mk <<= 1) {
    float f0 = __shfl_xor(e0, mk), f1 = __shfl_xor(e1, mk), f2 = __shfl_xor(e2, mk);
    int j0 = __shfl_xor(i0, mk), j1 = __shfl_xor(i1, mk), j2 = __shfl_xor(i2, mk);
    NN_INS(f0, j0);
    NN_INS(f1, j1);
    NN_INS(f2, j2);
  }
  if (tq == 0) {
    float a0 = fmaxf(e0, 1e-10f), a1 = fmaxf(e1, 1e-10f), a2 = fmaxf(e2, 1e-10f);
    float v0 = 1.f / a0, v1 = 1.f / a1, v2 = 1.f / a2;
    float inv = 1.f / (v0 + v1 + v2);
    int qi = t >> 3;
    sid[qi * 3 + 0] = i0; sid[qi * 3 + 1] = i1; sid[qi * 3 + 2] = i2;
    swt[qi * 3 + 0] = v0 * inv; swt[qi * 3 + 1] = v1 * inv; swt[qi * 3 + 2] = v2 * inv;
  }
  __syncthreads();
  // ---- interp + concat: thread t owns row r = t>>3, chunk lane s = t&7.
  // Chunks s+8i: i=0..3 -> points2 (interp), i=4,5 -> points1 (copy).
  // Row-invariant weights/ids/bases hoisted (no div, no redundant LDS reads).
  {
    int r = t >> 3, s = t & 7;
    size_t grow = (size_t)b * NN + qbase + r;
    unsigned short* xr = X + grow * CIN;
    const float* p2 = points2 + (size_t)b * MM * C2;
    float w0 = swt[r * 3], w1 = swt[r * 3 + 1], w2 = swt[r * 3 + 2];
    const float* a0 = p2 + (size_t)sid[r * 3 + 0] * C2;
    const float* a1 = p2 + (size_t)sid[r * 3 + 1] * C2;
    const float* a2 = p2 + (size_t)sid[r * 3 + 2] * C2;
#pragma unroll
    for (int i = 0; i < 4; ++i) {
      int c0 = (s + 8 * i) * 8;
      float4 x0 = *(const float4*)(a0 + c0), x1 = *(const float4*)(a0 + c0 + 4);
      float4 y0 = *(const float4*)(a1 + c0), y1 = *(const float4*)(a1 + c0 + 4);
      float4 z0 = *(const float4*)(a2 + c0), z1 = *(const float4*)(a2 + c0 + 4);
      uint4 o4;
      o4.x = pk2bf(w0 * x0.x + w1 * y0.x + w2 * z0.x, w0 * x0.y + w1 * y0.y + w2 * z0.y);
      o4.y = pk2bf(w0 * x0.z + w1 * y0.z + w2 * z0.z, w0 * x0.w + w1 * y0.w + w2 * z0.w);
      o4.z = pk2bf(w0 * x1.x + w1 * y1.x + w2 * z1.x, w0 * x1.y + w1 * y1.y + w2 * z1.y);
      o4.w = pk2bf(w0 * x1.z + w1 * y1.z + w2 * z1.z, w0 * x1.w + w1 * y1.w + w2 * z1.w);
      *(uint4*)(xr + c0) = o4;
    }
    const float* ap = points1 + grow * C1;
#pragma unroll
    for (int i = 0; i < 2; ++i) {
      int c0 = (s + 8 * i) * 8;
      float4 x0 = *(const float4*)(ap + c0), x1 = *(const float4*)(ap + c0 + 4);
      uint4 o4;
      o4.x = pk2bf(x0.x, x0.y); o4.y = pk2bf(x0.z, x0.w);
      o4.z = pk2bf(x1.x, x1.y); o4.w = pk2bf(x1.z, x1.w);
      *(uint4*)(xr + C2 + c0) = o4;
    }
  }
}

// ---------------------------------------------------------------- bf16 GEMM
// C[m][n] = sum_k A'[m][k] * Bt[n][k];  A' = FUSE ? relu(A*sc+sh) : A.
// Ping-pong A regs (afA/afB, no copies) + counted vmcnt before raw s_barrier:
// s_waitcnt vmcnt(4) waits ONLY the 4 older gload_lds (B stage); the 4 newer
// A-register loads stay in flight across the barrier (T4 minimum form).
__device__ inline void gload_lds16(const void* g, void* l) {
  __builtin_amdgcn_global_load_lds(
      (const __attribute__((address_space(1))) void*)g,
      (__attribute__((address_space(3))) void*)l, 16, 0, 0);
}

template <int K, bool FUSE>
__global__ __launch_bounds__(256, 3) void gemm_nt(const unsigned short* __restrict__ A,
                                                  const unsigned short* __restrict__ Bt,
                                                  unsigned short* __restrict__ C,
                                                  float* __restrict__ stats,
                                                  const float* __restrict__ statsPrev,
                                                  const float* __restrict__ g,
                                                  const float* __restrict__ be) {
  constexpr int NT = K / 64;
  __shared__ unsigned short lB[2][128 * 64];  // [buf][n][k] swizzled chunks
  __shared__ float sdat[256];
  __shared__ float lscsh[FUSE ? 512 : 4];
  int t = threadIdx.x;
  int lane = t & 63, w = t >> 6;
  // pair-XCD swizzle: the two 128-col panels of one row-tile get bids 8 apart
  int gb = blockIdx.x >> 4, rb = blockIdx.x & 15;
  int pq = rb >> 3, ti = (gb << 3) + (rb & 7);
  int m0 = ti * 128, n0 = pq * 128;
  int lrow = lane >> 3;                       // 0..7
  int lcol = (((lane & 7) ^ lrow) << 3);      // T2 source-side swizzled chunk

#define STAGE_B(buf, tt_)                                                      \
  {                                                                            \
    _Pragma("unroll") for (int i = 0; i < 4; ++i) {                            \
      int row = i * 32 + w * 8 + lrow;                                         \
      gload_lds16(Bt + (size_t)(n0 + row) * K + (tt_) * 64 + lcol,             \
                  &lB[buf][i * 2048 + w * 512]);                               \
    }                                                                          \
    asm volatile("" ::: "memory");  /* pin issue order: gloads before A */     \
  }

  const unsigned short* Ab = A + (size_t)(m0 + w * 32 + (lane & 15)) * K + (lane >> 4) * 8;
#define LOAD_A(dst, tt_)                                                       \
  {                                                                            \
    dst[0] = *(const uint4*)(Ab + (tt_) * 64);                                 \
    dst[1] = *(const uint4*)(Ab + (size_t)16 * K + (tt_) * 64);                \
    dst[2] = *(const uint4*)(Ab + (tt_) * 64 + 32);                            \
    dst[3] = *(const uint4*)(Ab + (size_t)16 * K + (tt_) * 64 + 32);           \
  }

  uint4 afA[4], afB[4];
  STAGE_B(0, 0);
  LOAD_A(afA, 0);
  sdat[t] = 0.f;
  if (FUSE) {
    float mean = statsPrev[t] * (1.f / ROWS);
    float var = statsPrev[256 + t] * (1.f / ROWS) - mean * mean;
    float sc = g[t] * rsqrtf(var + 1e-3f);
    lscsh[t] = sc;
    lscsh[256 + t] = be[t] - mean * sc;
  }
  __syncthreads();  // prologue: full drain, B(0) visible

  f32x4 acc[2][8] = {};

#define COMPUTE(buf, tt_, AF)                                                  \
  {                                                                            \
    _Pragma("unroll") for (int kk = 0; kk < 2; ++kk) {                         \
      int ko = kk * 32 + (lane >> 4) * 8;                                      \
      bf16x8 bfr[8];                                                           \
      _Pragma("unroll") for (int n2 = 0; n2 < 8; ++n2) {                       \
        int row = n2 * 16 + (lane & 15);                                       \
        bfr[n2] = *(const bf16x8*)&lB[buf][row * 64 + (ko ^ ((row & 7) << 3))];\
      }                                                                        \
      bf16x8 af[2];                                                            \
      _Pragma("unroll") for (int m = 0; m < 2; ++m) {                          \
        union { uint4 u; bf16x8 h; uint32_t wv[4]; } cv;                       \
        cv.u = AF[kk * 2 + m];                                                 \
        if (FUSE) {                                                            \
          int cb = (tt_) * 64 + ko;                                            \
          float4 sa = *(const float4*)&lscsh[cb];                              \
          float4 sb = *(const float4*)&lscsh[cb + 4];                          \
          float4 ha = *(const float4*)&lscsh[256 + cb];                        \
          float4 hb = *(const float4*)&lscsh[256 + cb + 4];                    \
          float scf[8] = {sa.x, sa.y, sa.z, sa.w, sb.x, sb.y, sb.z, sb.w};     \
          float shf[8] = {ha.x, ha.y, ha.z, ha.w, hb.x, hb.y, hb.z, hb.w};     \
          _Pragma("unroll") for (int q_ = 0; q_ < 4; ++q_) {                   \
            float lo = fmaxf(bflo(cv.wv[q_]) * scf[2 * q_] + shf[2 * q_], 0.f);\
            float hi = fmaxf(bfhi(cv.wv[q_]) * scf[2 * q_ + 1] + shf[2 * q_ + 1], 0.f); \
            cv.wv[q_] = pk2bf(lo, hi);                                         \
          }                                                                    \
        }                                                                      \
        af[m] = cv.h;                                                          \
      }                                                                        \
      _Pragma("unroll") for (int m = 0; m < 2; ++m)                            \
        _Pragma("unroll") for (int n2 = 0; n2 < 8; ++n2)                       \
          acc[m][n2] = __builtin_amdgcn_mfma_f32_16x16x32_bf16(af[m], bfr[n2], acc[m][n2], 0, 0, 0); \
    }                                                                          \
  }

#define CBAR()                                                                 \
  {                                                                            \
    asm volatile("s_waitcnt vmcnt(4)" ::: "memory");                           \
    __builtin_amdgcn_s_barrier();                                              \
  }

#pragma unroll
  for (int tt = 0; tt < NT; tt += 2) {
    STAGE_B(1, tt + 1);
    LOAD_A(afB, tt + 1);
    COMPUTE(0, tt, afA);
    CBAR();
    if (tt + 2 < NT) {
      STAGE_B(0, tt + 2);
      LOAD_A(afA, tt + 2);
    }
    COMPUTE(1, tt + 1, afB);
    if (tt + 2 < NT) CBAR();
  }
#undef STAGE_B
#undef LOAD_A
#undef COMPUTE
#undef CBAR

  // ---- C write (bf16, raw pre-BN values) ----
  int crow0 = m0 + w * 32 + (lane >> 4) * 4;
  int ccol0 = n0 + (lane & 15);
#pragma unroll
  for (int m = 0; m < 2; ++m)
#pragma unroll
    for (int n2 = 0; n2 < 8; ++n2) {
      size_t rb2 = (size_t)(crow0 + m * 16);
      int cc = ccol0 + n2 * 16;
#pragma unroll
      for (int j = 0; j < 4; ++j)
        C[(rb2 + j) * CO + cc] = f2bf(acc[m][n2][j]);
    }
  // ---- fused BN stats ----
#pragma unroll
  for (int n2 = 0; n2 < 8; ++n2) {
    float s = 0.f, qq = 0.f;
#pragma unroll
    for (int m = 0; m < 2; ++m)
#pragma unroll
      for (int j = 0; j < 4; ++j) { float v = acc[m][n2][j]; s += v; qq += v * v; }
    s += __shfl_xor(s, 16); qq += __shfl_xor(qq, 16);
    s += __shfl_xor(s, 32); qq += __shfl_xor(qq, 32);
    if (lane < 16) {
      int cl = n2 * 16 + lane;
      atomicAdd(&sdat[cl], s);
      atomicAdd(&sdat[128 + cl], qq);
    }
  }
  __syncthreads();
  if (t < 128) {
    atomicAdd(&stats[n0 + t], sdat[t]);
    atomicAdd(&stats[256 + n0 + t], sdat[128 + t]);
  }
}

// ------------------- BN+ReLU apply, fp32 out (finalize folded into prologue)
__global__ __launch_bounds__(256) void apply_f32(const unsigned short* __restrict__ Y,
                                                 const float* __restrict__ stats2,
                                                 const float* __restrict__ g,
                                                 const float* __restrict__ be,
                                                 float* __restrict__ out) {
  __shared__ float sc[256], sh[256];
  int t = threadIdx.x;
  {
    float mean = stats2[t] * (1.f / ROWS);
    float var = stats2[256 + t] * (1.f / ROWS) - mean * mean;
    float s = g[t] * rsqrtf(var + 1e-3f);
    sc[t] = s;
    sh[t] = be[t] - mean * s;
  }
  __syncthreads();
  size_t base = ((size_t)blockIdx.x * 256 + t) * 8;
  int c0 = (int)(base & 255);
  uint4 v = *(const uint4*)(Y + base);
  uint32_t wv[4] = {v.x, v.y, v.z, v.w};
  float o[8];
#pragma unroll
  for (int q = 0; q < 4; ++q) {
    o[2 * q]     = fmaxf(bflo(wv[q]) * sc[c0 + 2 * q] + sh[c0 + 2 * q], 0.f);
    o[2 * q + 1] = fmaxf(bfhi(wv[q]) * sc[c0 + 2 * q + 1] + sh[c0 + 2 * q + 1], 0.f);
  }
  *(float4*)(out + base) = make_float4(o[0], o[1], o[2], o[3]);
  *(float4*)(out + base + 4) = make_float4(o[4], o[5], o[6], o[7]);
}

extern "C" void kernel_launch(void* const* d_in, const int* in_sizes, int n_in,
                              void* d_out, int out_size, void* d_ws, size_t ws_size,
                              hipStream_t stream) {
  const float* xyz1    = (const float*)d_in[0];
  const float* xyz2    = (const float*)d_in[1];
  const float* points1 = (const float*)d_in[2];
  const float* points2 = (const float*)d_in[3];
  const float* W0      = (const float*)d_in[4];
  const float* g0      = (const float*)d_in[6];
  const float* be0     = (const float*)d_in[7];
  const float* W1      = (const float*)d_in[8];
  const float* g1      = (const float*)d_in[10];
  const float* be1     = (const float*)d_in[11];
  float* out = (float*)d_out;

  // workspace layout (bytes)
  char* ws = (char*)d_ws;
  unsigned short* X   = (unsigned short*)(ws);                       // ROWS*384 bf16 (reused for Y2)
  unsigned short* Y1  = (unsigned short*)(ws + 50331648);            // ROWS*256 bf16
  unsigned short* W0t = (unsigned short*)(ws + 50331648 + 33554432); // 384*256 bf16 (transposed)
  unsigned short* W1t = (unsigned short*)(ws + 50331648 + 33554432 + 196608);
  float* stats = (float*)(ws + 50331648 + 33554432 + 196608 + 131072); // 1024 f32
  unsigned short* Y2 = X;  // X buffer free after gemm1

  nn_interp<<<640 + BB * (NN / 32), 256, 0, stream>>>(xyz1, xyz2, points2, points1,
                                                      W0, W1, W0t, W1t, stats, X);
  gemm_nt<CIN, false><<<1024, 256, 0, stream>>>(X, W0t, Y1, stats, nullptr, nullptr, nullptr);
  gemm_nt<CO, true><<<1024, 256, 0, stream>>>(Y1, W1t, Y2, stats + 512, stats, g0, be0);
  apply_f32<<<(size_t)ROWS * CO / (256 * 8), 256, 0, stream>>>(Y2, stats + 512, g1, be1, out);
}